// Round 1
// 120.136 us; speedup vs baseline: 1.0774x; 1.0774x over previous
//
#include <hip/hip_runtime.h>
#include <math.h>

// B=4, T=48, W=8, H=8, C=32; d_ff=64; periods {2,3,4}. T%P==0 always.
// (1x1 + 3^4)/2 inception folded into one 81-tap conv (center tap 40).
// R15 = R14 + channel-split blocks for BOTH convs:
//   conv1: 576 blocks = (per,bb,tp,nh) — nh = output-channel half (GELU is
//          per-channel, split legal). w1 re-laid [tap][nh][1024].
//   conv2: 576 blocks = (per,bb,tp,kh) — kh = input-channel half (linear
//          partial sums via existing atomicAdd). w2 re-laid [tap][kh][1024].
//   h1 cells re-laid as 2 padded 3584-u16 halves (x-cell-style swizzle) so
//   conv2 fragment reads == conv1's pattern and halves stage independently.
//   LDS/block 76->52 KB => 3 blocks/CU, grid 576 all co-resident (12 w/CU).
//   conv2 upgraded from full-drain __syncthreads to the depth-2
//   wait-own-queue pipeline (counted vmcnt, never 0 in main loop).

typedef __attribute__((ext_vector_type(8))) short bf16x8;
typedef __attribute__((ext_vector_type(4))) float f32x4;
typedef unsigned short u16;

// ---- workspace offsets (u16 units) ----
#define XC 3200                 // u16 per x cell (10*10*32)
#define HC2 7168                // u16 per h1 cell (2 halves x 3584, padded)
#define XSEG 617600             // 193 * XC   (cell 192 = zero cell)
#define ZSEG_END 639104         // + 3*7168 h1 zero-cell writes
#define W1OFF 639104            // 165888 bf16: [tap 0..80][nh(2)][1024]
#define W2OFF 804992            // 165888 bf16: [tap 0..80][kh(2)][1024]
#define H1OFF 970880            // 3 periods x 193 cells x 7168
#define H1P 1383424             // per-period stride = 193*7168
#define PREP_N 970880           // end of weight segment
#define OUT_Q 98304             // out-init float4 count (393216 fp32)
#define PREP_TOT (PREP_N + OUT_Q)

#define WAITVM(N) asm volatile("s_waitcnt vmcnt(" #N ")" ::: "memory")
#define SBAR()    asm volatile("s_barrier" ::: "memory")

__device__ __forceinline__ u16 f2bf(float f) {
    unsigned u = __float_as_uint(f);
    unsigned r = u + 0x7fffu + ((u >> 16) & 1u);
    return (u16)(r >> 16);
}
__device__ __forceinline__ float gelu_exact(float v) {
    return 0.5f * v * (1.0f + erff(v * 0.7071067811865476f));
}

// async copy of 1 KB: 64 lanes x 16 B. LDS dest = wave-uniform base + lane*16.
__device__ __forceinline__ void cp1k(const u16* g, u16* l, int lane) {
    __builtin_amdgcn_global_load_lds(
        (const __attribute__((address_space(1))) unsigned int*)(g + lane * 8),
        (__attribute__((address_space(3))) unsigned int*)(l + lane * 8),
        16, 0, 0);
}

// ---- prep: x cells (swizzled) + h1 zero cells + weights + out = x ----
__global__ __launch_bounds__(256) void prep(
    const float* __restrict__ x,
    const float* __restrict__ w1_0, const float* __restrict__ w1_1,
    const float* __restrict__ w2_0, const float* __restrict__ w2_1,
    u16* __restrict__ ws, float* __restrict__ out) {
    int i = blockIdx.x * 256 + threadIdx.x;
    if (i < XSEG) {
        int cellidx = i / XC; int inner = i - cellidx * XC;
        int cellpos = inner >> 5; int low = inner & 31;
        int sc = low >> 3, jj = low & 7;
        int c = ((sc ^ (cellpos & 3)) << 3) + jj;
        int wp = cellpos / 10, hp = cellpos - (cellpos / 10) * 10;
        float v = 0.f;
        if (cellidx < 192 && wp >= 1 && wp <= 8 && hp >= 1 && hp <= 8)
            v = x[(cellidx * 64 + (wp - 1) * 8 + (hp - 1)) * 32 + c];
        ws[i] = f2bf(v);
    } else if (i < ZSEG_END) {
        int j = i - XSEG;                 // 3 h1 zero cells (full 7168 each)
        int per = j / 7168; int off = j - per * 7168;
        ws[H1OFF + per * H1P + 192 * 7168 + off] = 0;
    } else if (i < W2OFF) {
        // w1: [tap][nh][chunkh(128)*8+jj], chunkh = (quad*2+nq)*16+m
        int j = i - W1OFF;
        int tap = j >> 11; int r = j & 2047;
        int nh = r >> 10; int rr = r & 1023;
        int chunkh = rr >> 3, jj = rr & 7;
        int m = chunkh & 15, nq = (chunkh >> 4) & 1, quad = chunkh >> 5;
        int o = nh * 32 + nq * 16 + m, c = quad * 8 + jj;
        float v = 0.5f * w1_1[(o * 32 + c) * 81 + tap];
        if (tap == 40) v += 0.5f * w1_0[o * 32 + c];
        ws[i] = f2bf(v);
    } else if (i < PREP_N) {
        // w2: [tap][kh][chunkh(128)*8+jj], chunkh = (quad*2+nt)*16+m
        int j = i - W2OFF;
        int tap = j >> 11; int r = j & 2047;
        int kh = r >> 10; int rr = r & 1023;
        int chunkh = rr >> 3, jj = rr & 7;
        int m = chunkh & 15, nt = (chunkh >> 4) & 1, quad = chunkh >> 5;
        int o = nt * 16 + m, c = kh * 32 + quad * 8 + jj;
        float v = 0.5f * w2_1[(o * 64 + c) * 81 + tap];
        if (tap == 40) v += 0.5f * w2_0[o * 64 + c];
        ws[i] = f2bf(v);
    } else if (i < PREP_TOT) {
        int j = i - PREP_N;
        ((float4*)out)[j] = ((const float4*)x)[j];
    }
}

// cell index for (b, l2, q2): valid -> b*48 + l2*P + q2, else zero cell 192
template<int P>
__device__ __forceinline__ int cidx(int bb, int l2, int q2) {
    constexpr int L = 48 / P;
    return ((unsigned)l2 < (unsigned)L && (unsigned)q2 < (unsigned)P)
               ? bb * 48 + l2 * P + q2 : 192;
}

// ---- conv1 (C32 -> 32 of C64, nh half) + GELU.
// Block = 4 waves: (tloc, mh) = (wv>>1, wv&1). Depth-2 pipeline:
// 4-deep weight ring, wait-own-queue vmcnt BEFORE raw s_barrier. ----
template<int P>
__device__ __forceinline__ void conv1_body(
    const u16* __restrict__ xs, const u16* __restrict__ w1b,
    u16* __restrict__ h1, int tp, int bb, int nh,
    u16* __restrict__ s_w, u16* __restrict__ s_a) {
    constexpr int HB = (P == 2) ? 0 : (P == 3) ? H1P : 2 * H1P;

    int tid = threadIdx.x;
    int lane = tid & 63, wv = tid >> 6;
    int m = lane & 15, quad = lane >> 4;
    int tloc = wv >> 1, mh = wv & 1;

    int t0 = tp * 2, t1 = tp * 2 + 1;
    int l0 = t0 / P, q0 = t0 - l0 * P;
    int l1 = t1 / P, q1 = t1 - l1 * P;

    int sp[2];
#pragma unroll
    for (int mtl = 0; mtl < 2; ++mtl) {
        int pos = (mh * 2 + mtl) * 16 + m;
        sp[mtl] = (pos >> 3) * 10 + (pos & 7);
    }

    f32x4 acc[2][2];
#pragma unroll
    for (int mtl = 0; mtl < 2; ++mtl)
#pragma unroll
        for (int nq = 0; nq < 2; ++nq) acc[mtl][nq] = f32x4{0.f, 0.f, 0.f, 0.f};

    // weights chunk cgn = taps 3cgn..3cgn+2, this nh half: 6 pieces, pad 8
    // -> 2/wave uniform (k>=6 duplicates piece 5: same src+dst, benign)
    auto stageW = [&](int cgn) {
        const u16* src = w1b + (cgn * 3) * 2048 + nh * 1024;
        u16* dst = s_w + (cgn & 3) * 3072;
#pragma unroll
        for (int i = 0; i < 2; ++i) {
            int k = wv * 2 + i; if (k >= 6) k = 5;
            cp1k(src + (k >> 1) * 2048 + (k & 1) * 512, dst + k * 512, lane);
        }
    };
    // act group gg: 2 cells x 7 pieces = 14 padded to 16 -> 4/wave uniform
    auto stageA = [&](int gg) {
        int dl = gg / 3, dq = gg - (gg / 3) * 3;
        const u16* c0 = xs + cidx<P>(bb, l0 + dl - 1, q0 + dq - 1) * XC;
        const u16* c1 = xs + cidx<P>(bb, l1 + dl - 1, q1 + dq - 1) * XC;
#pragma unroll
        for (int i = 0; i < 4; ++i) {
            int k = wv * 4 + i; if (k >= 14) k = 13;
            int cell = k / 7, pc = k - (k / 7) * 7;
            cp1k((cell ? c1 : c0) + pc * 512,
                 s_a + (cell * 2 + (gg & 1)) * 3584 + pc * 512, lane);
        }
    };

    // prologue: chunks 0 (W+A0) and 1 (W). per-wave outstanding = 2+4+2
    stageW(0); stageA(0); stageW(1);

#pragma unroll 1
    for (int cg = 0; cg < 27; ++cg) {
        // issue chunk cg+2 (slot (cg+2)&3 distinct from readers cg-1,cg and
        // in-flight cg+1 under mod-4). A(g) rides with chunk 3g.
        if (cg < 25) {
            stageW(cg + 2);
            if ((cg + 2) % 3 == 0) stageA((cg + 2) / 3);
        }
        // wait own queue: chunk cg delivered; leave cg+1, cg+2 in flight.
        // P(chunk c) = 2 + (4 if c%3==0). cg%3==0 -> 4, else 8; tail 2, 0.
        if (cg == 25) { WAITVM(2); }
        else if (cg == 26) { WAITVM(0); }
        else if (cg % 3 == 0) { WAITVM(4); }
        else { WAITVM(8); }
        SBAR();   // publishes delivery of chunk cg + completion of cg-1

        int grp = cg / 3, part = cg - grp * 3;
        const u16* bw = s_w + (cg & 3) * 3072;
        const u16* ba = s_a + (tloc * 2 + (grp & 1)) * 3584;
        int dwb = part * 10;   // dw = part, dh = j
#pragma unroll
        for (int j = 0; j < 3; ++j) {
            const u16* tw = bw + j * 1024;
            bf16x8 wf[2];
#pragma unroll
            for (int nq = 0; nq < 2; ++nq)
                wf[nq] = *(const bf16x8*)(tw + (((quad * 2 + nq) * 16 + m) << 3));
            bf16x8 af[2];
#pragma unroll
            for (int mtl = 0; mtl < 2; ++mtl) {
                int cellpos = sp[mtl] + dwb + j;
                af[mtl] = *(const bf16x8*)(ba + cellpos * 32 +
                                           ((quad ^ (cellpos & 3)) << 3));
            }
#pragma unroll
            for (int mtl = 0; mtl < 2; ++mtl)
#pragma unroll
                for (int nq = 0; nq < 2; ++nq)
                    acc[mtl][nq] = __builtin_amdgcn_mfma_f32_16x16x32_bf16(
                        af[mtl], wf[nq], acc[mtl][nq], 0, 0, 0);
        }
    }

    // epilogue: GELU -> bf16 -> swizzled half-cell interior (x-cell-style)
    int t = tp * 2 + tloc;
    u16* hh = h1 + HB + (bb * 48 + t) * HC2 + nh * 3584;
#pragma unroll
    for (int mtl = 0; mtl < 2; ++mtl)
#pragma unroll
        for (int r = 0; r < 4; ++r) {
            int pos = (mh * 2 + mtl) * 16 + quad * 4 + r;
            int cellpos = ((pos >> 3) + 1) * 10 + (pos & 7) + 1;
#pragma unroll
            for (int nq = 0; nq < 2; ++nq) {
                int ol = nq * 16 + m;
                hh[cellpos * 32 + (((ol >> 3) ^ (cellpos & 3)) << 3) + (ol & 7)] =
                    f2bf(gelu_exact(acc[mtl][nq][r]));
            }
        }
    // zero the 36 border cellpos of both t half-cells (unique writer now)
#pragma unroll
    for (int it = 0; it < 5; ++it) {
        int k = it * 256 + tid;
        if (k < 1152) {
            int tb = k >= 576; int rr = k - tb * 576;
            int bp = rr >> 4, u = rr & 15;
            int cp;
            if (bp < 10) cp = bp;
            else if (bp < 20) cp = 90 + (bp - 10);
            else if (bp < 28) cp = (bp - 19) * 10;
            else cp = (bp - 27) * 10 + 9;
            unsigned int* h32 = (unsigned int*)(h1 + HB +
                (bb * 48 + tp * 2 + tb) * HC2 + nh * 3584);
            h32[cp * 16 + u] = 0;
        }
    }
}

__global__ __launch_bounds__(256, 3) void conv1_k(
    const u16* __restrict__ ws_x, const u16* __restrict__ ws_w1,
    u16* __restrict__ ws_h1) {
    __shared__ __align__(16) u16 s_w[4 * 3072];   // 24 KB weight ring (4-deep)
    __shared__ __align__(16) u16 s_a[4 * 3584];   // 28 KB -> 52 KB, 3 blk/CU
    int g = blockIdx.x;
    int jid = (g & 7) * 72 + (g >> 3);            // XCD-chunked, 576 = 8*72
    int per = jid / 192; int rem = jid - per * 192;
    int bb = rem / 48; int r2 = rem - bb * 48;
    int tp = r2 >> 1, nh = r2 & 1;
    if (per == 0)      conv1_body<2>(ws_x, ws_w1, ws_h1, tp, bb, nh, s_w, s_a);
    else if (per == 1) conv1_body<3>(ws_x, ws_w1, ws_h1, tp, bb, nh, s_w, s_a);
    else               conv1_body<4>(ws_x, ws_w1, ws_h1, tp, bb, nh, s_w, s_a);
}

// ---- conv2 (32 of C64 -> C32 partial, kh half). Same structure/pipeline
// as conv1; epilogue atomicAdds acc/3 into out (pre-filled with x). ----
template<int P>
__device__ __forceinline__ void conv2_body(
    const u16* __restrict__ h1, const u16* __restrict__ w2b,
    float* __restrict__ out, int tp, int bb, int kh,
    u16* __restrict__ s_w, u16* __restrict__ s_a) {
    constexpr int HB = (P == 2) ? 0 : (P == 3) ? H1P : 2 * H1P;

    int tid = threadIdx.x;
    int lane = tid & 63, wv = tid >> 6;
    int m = lane & 15, quad = lane >> 4;
    int tloc = wv >> 1, mh = wv & 1;

    int t0 = tp * 2, t1 = tp * 2 + 1;
    int l0 = t0 / P, q0 = t0 - l0 * P;
    int l1 = t1 / P, q1 = t1 - l1 * P;
    const u16* hb = h1 + HB;

    int sp[2];
#pragma unroll
    for (int mtl = 0; mtl < 2; ++mtl) {
        int pos = (mh * 2 + mtl) * 16 + m;
        sp[mtl] = (pos >> 3) * 10 + (pos & 7);
    }

    f32x4 acc[2][2];
#pragma unroll
    for (int mtl = 0; mtl < 2; ++mtl)
#pragma unroll
        for (int nt = 0; nt < 2; ++nt) acc[mtl][nt] = f32x4{0.f, 0.f, 0.f, 0.f};

    auto stageW = [&](int cgn) {
        const u16* src = w2b + (cgn * 3) * 2048 + kh * 1024;
        u16* dst = s_w + (cgn & 3) * 3072;
#pragma unroll
        for (int i = 0; i < 2; ++i) {
            int k = wv * 2 + i; if (k >= 6) k = 5;
            cp1k(src + (k >> 1) * 2048 + (k & 1) * 512, dst + k * 512, lane);
        }
    };
    auto stageA = [&](int gg) {
        int dl = gg / 3, dq = gg - (gg / 3) * 3;
        const u16* c0 = hb + cidx<P>(bb, l0 + dl - 1, q0 + dq - 1) * HC2 + kh * 3584;
        const u16* c1 = hb + cidx<P>(bb, l1 + dl - 1, q1 + dq - 1) * HC2 + kh * 3584;
#pragma unroll
        for (int i = 0; i < 4; ++i) {
            int k = wv * 4 + i; if (k >= 14) k = 13;
            int cell = k / 7, pc = k - (k / 7) * 7;
            cp1k((cell ? c1 : c0) + pc * 512,
                 s_a + (cell * 2 + (gg & 1)) * 3584 + pc * 512, lane);
        }
    };

    stageW(0); stageA(0); stageW(1);

#pragma unroll 1
    for (int cg = 0; cg < 27; ++cg) {
        if (cg < 25) {
            stageW(cg + 2);
            if ((cg + 2) % 3 == 0) stageA((cg + 2) / 3);
        }
        if (cg == 25) { WAITVM(2); }
        else if (cg == 26) { WAITVM(0); }
        else if (cg % 3 == 0) { WAITVM(4); }
        else { WAITVM(8); }
        SBAR();

        int grp = cg / 3, part = cg - grp * 3;
        const u16* bw = s_w + (cg & 3) * 3072;
        const u16* ba = s_a + (tloc * 2 + (grp & 1)) * 3584;
        int dwb = part * 10;
#pragma unroll
        for (int j = 0; j < 3; ++j) {
            const u16* tw = bw + j * 1024;
            bf16x8 wf[2];
#pragma unroll
            for (int nt = 0; nt < 2; ++nt)
                wf[nt] = *(const bf16x8*)(tw + (((quad * 2 + nt) * 16 + m) << 3));
            bf16x8 af[2];
#pragma unroll
            for (int mtl = 0; mtl < 2; ++mtl) {
                int cellpos = sp[mtl] + dwb + j;
                af[mtl] = *(const bf16x8*)(ba + cellpos * 32 +
                                           ((quad ^ (cellpos & 3)) << 3));
            }
#pragma unroll
            for (int mtl = 0; mtl < 2; ++mtl)
#pragma unroll
                for (int nt = 0; nt < 2; ++nt)
                    acc[mtl][nt] = __builtin_amdgcn_mfma_f32_16x16x32_bf16(
                        af[mtl], wf[nt], acc[mtl][nt], 0, 0, 0);
        }
    }

    // epilogue: out += acc/3 (softmax(ones) weights); out pre-filled with x
    int t = tp * 2 + tloc;
    float* orow = out + (bb * 48 + t) * 2048;
    const float s = 1.0f / 3.0f;
#pragma unroll
    for (int mtl = 0; mtl < 2; ++mtl)
#pragma unroll
        for (int nt = 0; nt < 2; ++nt)
#pragma unroll
            for (int r = 0; r < 4; ++r) {
                int pos = (mh * 2 + mtl) * 16 + quad * 4 + r;
                atomicAdd(&orow[pos * 32 + nt * 16 + m], acc[mtl][nt][r] * s);
            }
}

__global__ __launch_bounds__(256, 3) void conv2_k(
    const u16* __restrict__ ws_h1, const u16* __restrict__ ws_w2,
    float* __restrict__ out) {
    __shared__ __align__(16) u16 s_w[4 * 3072];   // 24 KB
    __shared__ __align__(16) u16 s_a[4 * 3584];   // 28 KB -> 52 KB, 3 blk/CU
    int g = blockIdx.x;
    int jid = (g & 7) * 72 + (g >> 3);            // same XCD mapping as conv1
    int per = jid / 192; int rem = jid - per * 192;
    int bb = rem / 48; int r2 = rem - bb * 48;
    int tp = r2 >> 1, kh = r2 & 1;
    if (per == 0)      conv2_body<2>(ws_h1, ws_w2, out, tp, bb, kh, s_w, s_a);
    else if (per == 1) conv2_body<3>(ws_h1, ws_w2, out, tp, bb, kh, s_w, s_a);
    else               conv2_body<4>(ws_h1, ws_w2, out, tp, bb, kh, s_w, s_a);
}

extern "C" void kernel_launch(void* const* d_in, const int* in_sizes, int n_in,
                              void* d_out, int out_size, void* d_ws, size_t ws_size,
                              hipStream_t stream) {
    const float* x    = (const float*)d_in[0];
    const float* w1_0 = (const float*)d_in[1];
    const float* w1_1 = (const float*)d_in[2];
    const float* w2_0 = (const float*)d_in[3];
    const float* w2_1 = (const float*)d_in[4];
    float* out = (float*)d_out;

    u16* ws = (u16*)d_ws;
    u16* ws_x  = ws;                 // 193 cells (192 real + zero)
    u16* ws_w1 = ws + W1OFF;
    u16* ws_w2 = ws + W2OFF;
    u16* ws_h1 = ws + H1OFF;         // 3 x 193 cells x 7168

    prep<<<(PREP_TOT + 255) / 256, 256, 0, stream>>>(
        x, w1_0, w1_1, w2_0, w2_1, ws, out);
    conv1_k<<<576, 256, 0, stream>>>(ws_x, ws_w1, ws_h1);
    conv2_k<<<576, 256, 0, stream>>>(ws_h1, ws_w2, out);
}